// Round 9
// baseline (929.928 us; speedup 1.0000x reference)
//
#include <hip/hip_runtime.h>

#define HID    64
#define TSTEPS 256
#define BATCH  2048

typedef float v2f __attribute__((ext_vector_type(2)));

// tanh(x) = 1 - 2/(exp2(2*log2(e)*x) + 1); exact at saturation
__device__ __forceinline__ float fast_tanh(float x) {
    float e = __builtin_amdgcn_exp2f(x * 2.8853900817779268f);
    float r = __builtin_amdgcn_rcpf(e + 1.0f);
    return fmaf(-2.0f, r, 1.0f);
}

// ds_swizzle xor-exchange within 32-lane halves (BitMode: xor=M, and=0x1F)
template <int M>
__device__ __forceinline__ float swz(float v) {
    return __int_as_float(__builtin_amdgcn_ds_swizzle(
        __float_as_int(v), (M << 10) | 0x1F));
}

// DPP move. 0xB1 quad_perm=lane^1, 0x4E quad_perm=lane^2, 0x128 row_ror:8 (==lane^8)
template <int CTRL>
__device__ __forceinline__ float dppx(float x) {
    int xi = __float_as_int(x);
    return __int_as_float(__builtin_amdgcn_update_dpp(xi, xi, CTRL, 0xF, 0xF, false));
}

__device__ __forceinline__ float bperm(int addr, float v) {
    return __int_as_float(__builtin_amdgcn_ds_bpermute(addr, __float_as_int(v)));
}

// packed f32 FMA, all operands 64-bit pairs (R7 errata)
__device__ __forceinline__ void pkfma(v2f& acc, v2f w, v2f hv) {
    asm("v_pk_fma_f32 %0, %1, %2, %0" : "+v"(acc) : "v"(w), "v"(hv));
}
// op_sel broadcast variants: both product halves use h.lo / h.hi (h IS a pair)
__device__ __forceinline__ void pkfma_lo(v2f& acc, v2f w, v2f h) {
    asm("v_pk_fma_f32 %0, %1, %2, %0 op_sel_hi:[1,0,1]"
        : "+v"(acc) : "v"(w), "v"(h));
}
__device__ __forceinline__ void pkfma_hi(v2f& acc, v2f w, v2f h) {
    asm("v_pk_fma_f32 %0, %1, %2, %0 op_sel:[0,1,0] op_sel_hi:[1,1,1]"
        : "+v"(acc) : "v"(w), "v"(h));
}

// full 64-lane sum via DPP rotates + row broadcasts; uniform result (lane 63)
__device__ __forceinline__ float wave_sum(float v) {
    v += dppx<0x121>(v);                       // ror:1
    v += dppx<0x122>(v);                       // ror:2
    v += dppx<0x124>(v);                       // ror:4
    v += dppx<0x128>(v);                       // ror:8  -> 16-row totals
    v += __int_as_float(__builtin_amdgcn_update_dpp(
            0, __float_as_int(v), 0x142, 0xA, 0xF, false));   // bcast15
    v += __int_as_float(__builtin_amdgcn_update_dpp(
            0, __float_as_int(v), 0x143, 0xC, 0xF, false));   // bcast31
    return __int_as_float(__builtin_amdgcn_readlane(__float_as_int(v), 63));
}

__device__ __forceinline__ constexpr int rev3(int x) {   // 3-bit reversal
    return ((x & 1) << 2) | (x & 2) | ((x >> 2) & 1);
}

__global__ __launch_bounds__(256) __attribute__((amdgpu_waves_per_eu(2, 2)))
void hnn_rk4_kernel(
        const float* __restrict__ tarr,
        const float* __restrict__ x0,
        const float* __restrict__ W1,
        const float* __restrict__ b1,
        const float* __restrict__ W2,
        const float* __restrict__ b2,
        const float* __restrict__ W3,
        float* __restrict__ out)
{
    const int lane = threadIdx.x & 63;
    const int wid  = threadIdx.x >> 6;
    const int b    = blockIdx.x * 4 + wid;     // one wave per batch element

    // 8x8 lane grid; lane (rr,cc) owns W2 rows 8rr..+7 x cols 8cc..+7 and
    // hidden unit uo = 8rr + rev3(cc). SINGLE weight block serves fwd + bwd.
    const int rr = lane >> 3, cc = lane & 7;
    const int pc = rev3(cc);
    const int uo = 8 * rr + pc;
    const int vu = 8 * cc + rev3(rr);          // unit whose u this lane ends up holding

    const float dt  = tarr[1] - tarr[0];
    const float hdt = 0.5f * dt;
    const float sdt = dt * (1.0f / 6.0f);

    // per-own-unit params
    const float w1a = W1[2 * uo + 0];
    const float w1b = W1[2 * uo + 1];
    const float b1i = b1[uo];
    const float b2i = b2[uo];
    const float w3i = W3[uo];
    // W1 pair of the HELD unit vu (landing-agnostic dHdx wave-sum)
    const float w1va = W1[2 * vu + 0];
    const float w1vb = W1[2 * vu + 1];

    // forward broadcast: h1[8cc+t] owned by lane 8cc+rev3(t) -> base + const offsets
    const int base_c = cc * 32;                // (8cc)*4
    // backward broadcast: g2[8rr+(2m)^pc] owned by lane 8rr + (rev3(2m)^cc)
    const int base_r = rr * 32;
    int ga[8];
#pragma unroll
    for (int m = 0; m < 4; ++m) {
        const int e = rev3(2 * m);             // {0,2,1,3}
        ga[2 * m + 0] = base_r + ((e ^ cc) * 4);
        ga[2 * m + 1] = base_r + (((e ^ 4) ^ cc) * 4);
    }
    int a32 = (lane ^ 32) * 4;                 // rr-bit2 exchange
    int ath = (8 * cc + rr) * 4;               // owner lane of h1[vu]

    // forward weights, paired over output rows, positions pre-XORed by pc:
    //   wsF[t][m] = ( W2[8rr+((2m)^pc)][8cc+t], W2[8rr+((2m+1)^pc)][8cc+t] )
    v2f wsF[8][4];
#pragma unroll
    for (int t = 0; t < 8; ++t) {
#pragma unroll
        for (int m = 0; m < 4; ++m) {
            v2f f;
            f.x = W2[(8 * rr + ((2 * m)     ^ pc)) * HID + 8 * cc + t];
            f.y = W2[(8 * rr + ((2 * m + 1) ^ pc)) * HID + 8 * cc + t];
            wsF[t][m] = f;
        }
    }
#pragma unroll
    for (int t = 0; t < 8; ++t)
#pragma unroll
        for (int m = 0; m < 4; ++m)
            asm("" : "+v"(wsF[t][m]));

    const bool rb0 = lane & 8, rb1 = lane & 16, rb2 = lane & 32;

    float q = x0[2 * b + 0];
    float p = x0[2 * b + 1];

    if (lane == 0) {
        out[2 * b + 0] = q;
        out[2 * b + 1] = p;
    }

    auto dynamics = [&](float xq, float xp, float& kq, float& kp) {
        // layer 1 (own unit)
        const float h1 = fast_tanh(fmaf(w1a, xq, fmaf(w1b, xp, b1i)));

        // ---- forward: pre2 = W2 h1 + b2 ----
        // hpair[k] = (h1[8cc+2k], h1[8cc+2k+1]); offsets rev3(t)*4 are constants
        v2f hp0, hp1, hp2, hp3;
        hp0.x = bperm(base_c + 0 * 4, h1);  hp0.y = bperm(base_c + 4 * 4, h1);
        hp1.x = bperm(base_c + 2 * 4, h1);  hp1.y = bperm(base_c + 6 * 4, h1);
        hp2.x = bperm(base_c + 1 * 4, h1);  hp2.y = bperm(base_c + 5 * 4, h1);
        hp3.x = bperm(base_c + 3 * 4, h1);  hp3.y = bperm(base_c + 7 * 4, h1);
        // prefetch h1 of held unit vu (same DS batch)
        const float h1v = bperm(ath, h1);

        v2f P0 = {0.f, 0.f}, P1 = {0.f, 0.f}, P2 = {0.f, 0.f}, P3 = {0.f, 0.f};
        // t=0,1 from hp0 (lo,hi), t=2,3 from hp1, t=4,5 from hp2, t=6,7 from hp3
        pkfma_lo(P0, wsF[0][0], hp0); pkfma_lo(P1, wsF[0][1], hp0);
        pkfma_lo(P2, wsF[0][2], hp0); pkfma_lo(P3, wsF[0][3], hp0);
        pkfma_hi(P0, wsF[1][0], hp0); pkfma_hi(P1, wsF[1][1], hp0);
        pkfma_hi(P2, wsF[1][2], hp0); pkfma_hi(P3, wsF[1][3], hp0);
        pkfma_lo(P0, wsF[2][0], hp1); pkfma_lo(P1, wsF[2][1], hp1);
        pkfma_lo(P2, wsF[2][2], hp1); pkfma_lo(P3, wsF[2][3], hp1);
        pkfma_hi(P0, wsF[3][0], hp1); pkfma_hi(P1, wsF[3][1], hp1);
        pkfma_hi(P2, wsF[3][2], hp1); pkfma_hi(P3, wsF[3][3], hp1);
        pkfma_lo(P0, wsF[4][0], hp2); pkfma_lo(P1, wsF[4][1], hp2);
        pkfma_lo(P2, wsF[4][2], hp2); pkfma_lo(P3, wsF[4][3], hp2);
        pkfma_hi(P0, wsF[5][0], hp2); pkfma_hi(P1, wsF[5][1], hp2);
        pkfma_hi(P2, wsF[5][2], hp2); pkfma_hi(P3, wsF[5][3], hp2);
        pkfma_lo(P0, wsF[6][0], hp3); pkfma_lo(P1, wsF[6][1], hp3);
        pkfma_lo(P2, wsF[6][2], hp3); pkfma_lo(P3, wsF[6][3], hp3);
        pkfma_hi(P0, wsF[7][0], hp3); pkfma_hi(P1, wsF[7][1], hp3);
        pkfma_hi(P2, wsF[7][2], hp3); pkfma_hi(P3, wsF[7][3], hp3);

        // uniform scatter-reduce over cc bits (proven R6/R8)
        P0.x += dppx<0xB1>(P2.x);  P0.y += dppx<0xB1>(P2.y);
        P1.x += dppx<0xB1>(P3.x);  P1.y += dppx<0xB1>(P3.y);
        P0.x += dppx<0x4E>(P1.x);  P0.y += dppx<0x4E>(P1.y);
        const float pre2 = P0.x + swz<4>(P0.y) + b2i;

        const float h2 = fast_tanh(pre2);
        const float g2 = w3i * fmaf(-h2, h2, 1.0f);

        // ---- backward: u = W2^T g2, reusing wsF ----
        // gbp[m] = (g2[8rr+(2m)^pc], g2[8rr+(2m+1)^pc])
        v2f gbp0, gbp1, gbp2, gbp3;
        gbp0.x = bperm(ga[0], g2);  gbp0.y = bperm(ga[1], g2);
        gbp1.x = bperm(ga[2], g2);  gbp1.y = bperm(ga[3], g2);
        gbp2.x = bperm(ga[4], g2);  gbp2.y = bperm(ga[5], g2);
        gbp3.x = bperm(ga[6], g2);  gbp3.y = bperm(ga[7], g2);

        // uP[t] = partial of u[8cc+t] over this lane's 8 rows
        float uP[8];
#pragma unroll
        for (int t = 0; t < 8; ++t) {
            v2f A = {0.f, 0.f};
            pkfma(A, wsF[t][0], gbp0);
            pkfma(A, wsF[t][1], gbp1);
            pkfma(A, wsF[t][2], gbp2);
            pkfma(A, wsF[t][3], gbp3);
            uP[t] = A.x + A.y;
        }

        // reduce over rr lanes (bits 3,4,5), bit-reversed landing (proven R5):
        float v4[4];
#pragma unroll
        for (int t = 0; t < 4; ++t) {
            float keep = rb0 ? uP[t + 4] : uP[t];
            float send = rb0 ? uP[t]     : uP[t + 4];
            v4[t] = keep + dppx<0x128>(send);
        }
        float w2v[2];
#pragma unroll
        for (int k = 0; k < 2; ++k) {
            float keep = rb1 ? v4[k + 2] : v4[k];
            float send = rb1 ? v4[k]     : v4[k + 2];
            w2v[k] = keep + swz<16>(send);
        }
        float keep3 = rb2 ? w2v[1] : w2v[0];
        float send3 = rb2 ? w2v[0] : w2v[1];
        const float uv = keep3 + bperm(a32, send3);   // = u[vu], stays here

        // dH/dx contribution of unit vu; wave_sum is landing-agnostic
        const float g1v = uv * fmaf(-h1v, h1v, 1.0f);

        kq =  wave_sum(g1v * w1vb);   //  dH/dp
        kp = -wave_sum(g1v * w1va);   // -dH/dq
    };

#pragma unroll 1
    for (int s = 0; s < TSTEPS - 1; ++s) {
        float kq1, kp1, kq2, kp2, kq3, kp3, kq4, kp4;
        dynamics(q, p, kq1, kp1);
        dynamics(fmaf(hdt, kq1, q), fmaf(hdt, kp1, p), kq2, kp2);
        dynamics(fmaf(hdt, kq2, q), fmaf(hdt, kp2, p), kq3, kp3);
        dynamics(fmaf(dt,  kq3, q), fmaf(dt,  kp3, p), kq4, kp4);
        q = fmaf(sdt, (kq1 + kq4) + 2.0f * (kq2 + kq3), q);
        p = fmaf(sdt, (kp1 + kp4) + 2.0f * (kp2 + kp3), p);
        if (lane == 0) {
            out[(s + 1) * (BATCH * 2) + 2 * b + 0] = q;
            out[(s + 1) * (BATCH * 2) + 2 * b + 1] = p;
        }
    }
}

extern "C" void kernel_launch(void* const* d_in, const int* in_sizes, int n_in,
                              void* d_out, int out_size, void* d_ws, size_t ws_size,
                              hipStream_t stream) {
    const float* t  = (const float*)d_in[0];
    const float* x0 = (const float*)d_in[1];
    const float* W1 = (const float*)d_in[2];
    const float* b1 = (const float*)d_in[3];
    const float* W2 = (const float*)d_in[4];
    const float* b2 = (const float*)d_in[5];
    const float* W3 = (const float*)d_in[6];
    // d_in[7] = b3: additive constant in H, cancels in dH/dx — unused.

    hnn_rk4_kernel<<<dim3(BATCH / 4), dim3(256), 0, stream>>>(
        t, x0, W1, b1, W2, b2, W3, (float*)d_out);
}